// Round 6
// baseline (669.350 us; speedup 1.0000x reference)
//
#include <hip/hip_runtime.h>

// MultiHeadedAttention: out = ((softmax(softmax(QK^T/8)+softmax(mask/128)))V) @ Wo
// Q,K,V (128,512,768) fp32 -> flat [65536][768]. Attention slice (l,h) = rows
// l*128..+127, cols h*64..+63 of the flat projection buffers.
// R5 post-mortem: vt re-swizzle FAILED its pre-committed test (conflicts
// 1.57e7 -> 1.73e7) -> reverted to the R1 vt mapping exactly. gemm8 occupancy
// decoded: LDS 128KB -> 1 block/CU (and acc=128 regs blocks a 2nd block via
// the register file) -> 768 blocks = 3.0 exact rotations; no tail problem.
// This round (single variable): remove inter-launch drain boundaries on the
// independent Q/K paths. convb2 converts Q and K in one launch (grid y=2);
// gemm8x2 runs the Q-proj and K-proj GEMMs in one launch (grid (768,2),
// uniform pointer-select by blockIdx.y, single body instance). Kernel
// internals byte-identical to the proven R1 code.
//   convb: fp32->bf16 L3-staging. gemm8: R1 cross-phase ds_read prefetch,
//   vmcnt 6/4/0. attn: R1 (32KB, ps column-halves, exp2-folded dual softmax).

typedef __attribute__((ext_vector_type(8))) __bf16 bf16x8;
typedef __attribute__((ext_vector_type(4))) __bf16 bf16x4;
typedef __attribute__((ext_vector_type(4))) float f32x4;

#define DM 768
#define LOG2E 1.44269504f

__device__ __forceinline__ unsigned short f2bf(float x) {
  unsigned u = __float_as_uint(x);
  u += 0x7FFFu + ((u >> 16) & 1u);   // RNE
  return (unsigned short)(u >> 16);
}

__device__ __forceinline__ void gl_lds16(const void* g, void* l) {
  __builtin_amdgcn_global_load_lds(
      (const __attribute__((address_space(1))) unsigned int*)g,
      (__attribute__((address_space(3))) unsigned int*)l, 16, 0, 0);
}

// ---------------- prep: transpose+convert 4 weights to bf16 [op][n][k] ----------------
__global__ __launch_bounds__(256) void prep_w(const float* __restrict__ w0,
                                              const float* __restrict__ w1,
                                              const float* __restrict__ w2,
                                              const float* __restrict__ w3,
                                              unsigned short* __restrict__ wt) {
  __shared__ float t[32][33];
  const int op = blockIdx.z;
  const float* w = (op == 0) ? w0 : (op == 1) ? w1 : (op == 2) ? w2 : w3;
  unsigned short* o = wt + (size_t)op * DM * DM;
  const int n0 = blockIdx.x * 32, k0 = blockIdx.y * 32;
  const int tx = threadIdx.x & 31, ty = threadIdx.x >> 5;   // ty 0..7
#pragma unroll
  for (int r = 0; r < 4; ++r)
    t[r * 8 + ty][tx] = w[(size_t)(k0 + r * 8 + ty) * DM + n0 + tx];
  __syncthreads();
#pragma unroll
  for (int r = 0; r < 4; ++r)
    o[(size_t)(n0 + r * 8 + ty) * DM + k0 + tx] = f2bf(t[tx][r * 8 + ty]);
}

// ------- prep: mm = softmax(mask/128, axis=-1) * log2e, fp32 [128][128] ---------------
__global__ void prep_m(const float* __restrict__ mask, float* __restrict__ mm) {
  int row = blockIdx.x;
  int t = threadIdx.x;  // 64 threads
  float a = mask[row * 128 + t] * (1.0f / 128.0f);
  float b = mask[row * 128 + t + 64] * (1.0f / 128.0f);
  float mx = fmaxf(a, b);
  for (int s = 1; s < 64; s <<= 1) mx = fmaxf(mx, __shfl_xor(mx, s));
  float ea = __expf(a - mx), eb = __expf(b - mx);
  float sum = ea + eb;
  for (int s = 1; s < 64; s <<= 1) sum += __shfl_xor(sum, s);
  float inv = LOG2E / sum;               // prescale by log2e for attn's exp2 path
  mm[row * 128 + t] = ea * inv;
  mm[row * 128 + t + 64] = eb * inv;
}

// ---------------- conv: fp32 -> bf16, vectorized (8 elems/thread/iter) ----------------
__device__ __forceinline__ void convb_body(const float* __restrict__ in,
                                           unsigned short* __restrict__ out, int n8) {
  int i = blockIdx.x * 256 + threadIdx.x;
  const int stride = gridDim.x * 256;
  for (; i < n8; i += stride) {
    const float4 a = ((const float4*)in)[(size_t)i * 2];
    const float4 b = ((const float4*)in)[(size_t)i * 2 + 1];
    ushort4 lo = {f2bf(a.x), f2bf(a.y), f2bf(a.z), f2bf(a.w)};
    ushort4 hi = {f2bf(b.x), f2bf(b.y), f2bf(b.z), f2bf(b.w)};
    ((ushort4*)out)[(size_t)i * 2] = lo;
    ((ushort4*)out)[(size_t)i * 2 + 1] = hi;
  }
}

__global__ __launch_bounds__(256) void convb(const float* __restrict__ in,
                                             unsigned short* __restrict__ out, int n8) {
  convb_body(in, out, n8);
}

// two independent tensors in one launch (no inter-launch drain boundary)
__global__ __launch_bounds__(256) void convb2(const float* __restrict__ in0,
                                              const float* __restrict__ in1,
                                              unsigned short* __restrict__ out0,
                                              unsigned short* __restrict__ out1, int n8) {
  const int op = blockIdx.y;
  convb_body(op ? in1 : in0, op ? out1 : out0, n8);
}

// ---------------- gemm8: [65536 x 768] bf16 A @ [768 x 768] Bt(n-major bf16) ----------
__device__ __forceinline__ void stage_tile(const unsigned short* __restrict__ src,
                                           int row0, int kcol, char* slotbase, int tid) {
  const int wid = tid >> 6, lane = tid & 63;
#pragma unroll
  for (int s = 0; s < 2; ++s) {
    const int row = s * 128 + wid * 16 + (lane >> 2);
    const int slot = lane & 3;
    gl_lds16(src + (size_t)(row0 + row) * DM + kcol + ((slot ^ ((row >> 1) & 3)) * 8),
             slotbase + s * 8192 + wid * 1024);
  }
}

template <bool OUT_BF16>
__device__ __forceinline__ void gemm8_body(const unsigned short* __restrict__ A,
                                           const unsigned short* __restrict__ Bt,
                                           const float* __restrict__ bias,
                                           void* __restrict__ Outp, char* smem) {
  const int tid = threadIdx.x, lane = tid & 63, wid = tid >> 6;
  const int cl = lane & 15, g = lane >> 4;
  const int wm = wid >> 2, wn = wid & 3;
  const int bid = blockIdx.x;
  const int xcd = bid & 7, bi = bid >> 3;        // 768 = 8 xcd * (32 m * 3 n)
  const int m0 = (xcd * 32 + bi / 3) * 256;
  const int n0 = (bi % 3) * 256;

  f32x4 acc[8][4] = {};

  auto aslot = [&](int t) { return smem + (t & 3) * 16384; };
  auto bslot = [&](int t) { return smem + 65536 + (t & 3) * 16384; };

  auto lda = [&](bf16x8* af, int t, int half) {
#pragma unroll
    for (int mi = 0; mi < 4; ++mi) {
      const int r = wm * 128 + (half * 4 + mi) * 16 + cl;
      af[mi] = *(const bf16x8*)(aslot(t) + r * 64 + ((g ^ ((r >> 1) & 3)) * 16));
    }
  };
  auto ldb = [&](bf16x8* bf, int t) {
#pragma unroll
    for (int ni = 0; ni < 4; ++ni) {
      const int r = wn * 64 + ni * 16 + cl;
      bf[ni] = *(const bf16x8*)(bslot(t) + r * 64 + ((g ^ ((r >> 1) & 3)) * 16));
    }
  };
  auto mfma16 = [&](bf16x8* af, bf16x8* bf, int half) {
    __builtin_amdgcn_s_setprio(1);
#pragma unroll
    for (int mi = 0; mi < 4; ++mi)
#pragma unroll
      for (int ni = 0; ni < 4; ++ni)
        acc[half * 4 + mi][ni] = __builtin_amdgcn_mfma_f32_16x16x32_bf16(
            af[mi], bf[ni], acc[half * 4 + mi][ni], 0, 0, 0);
    __builtin_amdgcn_s_setprio(0);
  };

  // One K-step with cross-phase prefetch. Entering: (af0, bfc) hold step-t frags.
  // ph0: stage A(t+3); drain vmcnt so B(t+1) landed (all waves) -> barrier;
  //      issue af1 reads; MFMA half0 (overlaps af1 reads).
  // ph1: stage B(t+3); issue (t+1) frag reads (slot sealed by ph0 barrier);
  //      MFMA half1 (overlaps t+1 reads); end barrier (seals slot reuse WAR).
  auto gstep = [&](int t, bool stg, int vm, bf16x8* af0, bf16x8* bfc,
                   bf16x8* af0n, bf16x8* bfn, bool last) {
    bf16x8 af1[4];
    if (stg) stage_tile(A, m0, (t + 3) * 32, aslot(t + 3), tid);
    if (vm == 6)      asm volatile("s_waitcnt vmcnt(6)" ::: "memory");
    else if (vm == 4) asm volatile("s_waitcnt vmcnt(4)" ::: "memory");
    else              asm volatile("s_waitcnt vmcnt(0)" ::: "memory");
    __builtin_amdgcn_s_barrier();
    lda(af1, t, 1);                       // ds reads overlap half0 MFMAs
    mfma16(af0, bfc, 0);
    if (stg) stage_tile(Bt, n0, (t + 3) * 32, bslot(t + 3), tid);
    if (!last) {
      lda(af0n, t + 1, 0);                // ds reads overlap half1 MFMAs
      ldb(bfn, t + 1);
    }
    mfma16(af1, bfc, 1);
    __builtin_amdgcn_s_barrier();
  };

  // prologue: tiles 0,1,2 staged; tile 0 landed; preload step-0 frags.
  stage_tile(A, m0, 0, aslot(0), tid);   stage_tile(Bt, n0, 0, bslot(0), tid);
  stage_tile(A, m0, 32, aslot(1), tid);  stage_tile(Bt, n0, 32, bslot(1), tid);
  stage_tile(A, m0, 64, aslot(2), tid);  stage_tile(Bt, n0, 64, bslot(2), tid);
  asm volatile("s_waitcnt vmcnt(8)" ::: "memory");   // A0,B0 landed
  __builtin_amdgcn_s_barrier();

  bf16x8 afA[4], bfA[4], afB[4], bfB[4];
  lda(afA, 0, 0);
  ldb(bfA, 0);

#pragma unroll 1
  for (int t = 0; t < 20; t += 2) {
    gstep(t, true, 6, afA, bfA, afB, bfB, false);
    gstep(t + 1, true, 6, afB, bfB, afA, bfA, false);
  }
  gstep(20, true, 6, afA, bfA, afB, bfB, false);
  gstep(21, false, 4, afB, bfB, afA, bfA, false);
  gstep(22, false, 0, afA, bfA, afB, bfB, false);
  gstep(23, false, 0, afB, bfB, afA, bfA, true);

  float bb[4];
#pragma unroll
  for (int ni = 0; ni < 4; ++ni) bb[ni] = bias[n0 + wn * 64 + ni * 16 + cl];
#pragma unroll
  for (int mi = 0; mi < 8; ++mi) {
    const int row = m0 + wm * 128 + mi * 16 + g * 4;
#pragma unroll
    for (int ni = 0; ni < 4; ++ni) {
      const int col = n0 + wn * 64 + ni * 16 + cl;
#pragma unroll
      for (int e = 0; e < 4; ++e) {
        float v = acc[mi][ni][e] + bb[ni];
        if constexpr (OUT_BF16)
          ((unsigned short*)Outp)[(size_t)(row + e) * DM + col] = f2bf(v);
        else
          ((float*)Outp)[(size_t)(row + e) * DM + col] = v;
      }
    }
  }
}

template <bool OUT_BF16>
__global__ __launch_bounds__(512, 2) void gemm8(const unsigned short* __restrict__ A,
                                                const unsigned short* __restrict__ Bt,
                                                const float* __restrict__ bias,
                                                void* __restrict__ Outp) {
  __shared__ char smem[131072];   // A ring 4x16KB @0, B ring 4x16KB @65536
  gemm8_body<OUT_BF16>(A, Bt, bias, Outp, smem);
}

// two independent projections in one launch; blockIdx.y selects op (uniform),
// single body instance -> identical codegen, no inter-launch drain boundary.
__global__ __launch_bounds__(512, 2) void gemm8x2(const unsigned short* __restrict__ A0,
                                                  const unsigned short* __restrict__ Bt0,
                                                  const float* __restrict__ b0,
                                                  unsigned short* __restrict__ O0,
                                                  const unsigned short* __restrict__ A1,
                                                  const unsigned short* __restrict__ Bt1,
                                                  const float* __restrict__ b1,
                                                  unsigned short* __restrict__ O1) {
  __shared__ char smem[131072];
  const int op = blockIdx.y;
  gemm8_body<true>(op ? A1 : A0, op ? Bt1 : Bt0, op ? b1 : b0,
                   op ? (void*)O1 : (void*)O0, smem);
}

// ---------------- attention: 8 waves x 16 q-rows, swapped QK^T, exp2 softmax ----------
__global__ __launch_bounds__(512) void attn_k(const unsigned short* __restrict__ qp,
                                              const unsigned short* __restrict__ kp,
                                              const unsigned short* __restrict__ vp,
                                              const float* __restrict__ mm,
                                              unsigned short* __restrict__ xout) {
  __shared__ char smem[32768];
  // [0,16384): ks [128][64] bf16, 16B-granule XOR swizzle (gi ^= row&7); after
  //            the post-QK^T barrier, reused as ps [128][64] bf16 COLUMN-HALF
  //            of P (two passes: cols 0..63 then 64..127), 8B granules,
  //            gi ^= (q&3)<<2.
  // [16384,32768): vt [64][128] bf16, 4-elem granule swizzle (R1-proven):
  //            phys = kq ^ ((d>>3)<<2).
  unsigned short* vt = (unsigned short*)(smem + 16384);

  const int tid = threadIdx.x, lane = tid & 63, wid = tid >> 6;
  const int cl = lane & 15, g = lane >> 4;
  const int h = blockIdx.x, l = blockIdx.y;
  const size_t base = (size_t)l * 128 * DM + h * 64;
  const int q = wid * 16 + cl;                   // this lane's q-row

#pragma unroll
  for (int p = 0; p < 2; ++p) {
    const int chunk = p * 8 + wid;              // 0..15, 1KB each
    const int row = chunk * 8 + (lane >> 3);    // 128B rows
    const int gi = (lane & 7) ^ (row & 7);
    gl_lds16(kp + base + (size_t)row * DM + gi * 8, smem + chunk * 1024);
  }
  if (tid < 256) {
    const int dc = (tid & 7) * 8;
    const int kq = tid >> 3;
    const int pg = (kq ^ ((tid & 7) << 2));
    int4 r0 = *(const int4*)&vp[base + (size_t)(kq * 4 + 0) * DM + dc];
    int4 r1 = *(const int4*)&vp[base + (size_t)(kq * 4 + 1) * DM + dc];
    int4 r2 = *(const int4*)&vp[base + (size_t)(kq * 4 + 2) * DM + dc];
    int4 r3 = *(const int4*)&vp[base + (size_t)(kq * 4 + 3) * DM + dc];
    const unsigned short* u0 = (const unsigned short*)&r0;
    const unsigned short* u1 = (const unsigned short*)&r1;
    const unsigned short* u2 = (const unsigned short*)&r2;
    const unsigned short* u3 = (const unsigned short*)&r3;
#pragma unroll
    for (int j = 0; j < 8; ++j) {
      ushort4 w = {u0[j], u1[j], u2[j], u3[j]};
      *(ushort4*)&vt[(dc + j) * 128 + pg * 4] = w;
    }
  }
  bf16x8 qf[2];
#pragma unroll
  for (int ksr = 0; ksr < 2; ++ksr)
    qf[ksr] = *(const bf16x8*)&qp[base + (size_t)q * DM + ksr * 32 + g * 8];
  __syncthreads();

  f32x4 sacc[8] = {};
  __builtin_amdgcn_s_setprio(1);
#pragma unroll
  for (int ksr = 0; ksr < 2; ++ksr) {
#pragma unroll
    for (int kf = 0; kf < 8; ++kf) {
      const int row = kf * 16 + cl;
      const int gi = (ksr * 4 + g) ^ (row & 7);
      bf16x8 kfr = *(const bf16x8*)(smem + row * 128 + gi * 16);
      sacc[kf] = __builtin_amdgcn_mfma_f32_16x16x32_bf16(kfr, qf[ksr], sacc[kf], 0, 0, 0);
    }
  }
  __builtin_amdgcn_s_setprio(0);
  __syncthreads();   // all waves' ks reads done before any ps write (ps aliases ks)

  // ---- dual softmax, exp2-folded, no max subtraction (inputs bounded)
  bf16x4 pk[8];
  {
    float4 mrow[8];
#pragma unroll
    for (int kf = 0; kf < 8; ++kf)
      mrow[kf] = *(const float4*)&mm[q * 128 + kf * 16 + g * 4];
    float sm = 0.f;
#pragma unroll
    for (int kf = 0; kf < 8; ++kf)
#pragma unroll
      for (int e = 0; e < 4; ++e) {
        float p = exp2f(sacc[kf][e] * (0.125f * LOG2E));   // = exp(s/8)
        sacc[kf][e] = p;
        sm += p;
      }
    sm += __shfl_xor(sm, 16); sm += __shfl_xor(sm, 32);
    const float inv2e = LOG2E / sm;
    float s2 = 0.f;
#pragma unroll
    for (int kf = 0; kf < 8; ++kf)
#pragma unroll
      for (int e = 0; e < 4; ++e) {
        // mrow prescaled by log2e: exp(p/sm + m) = exp2(p*inv2e + m*log2e)
        float p = exp2f(fmaf(sacc[kf][e], inv2e, ((const float*)&mrow[kf])[e]));
        sacc[kf][e] = p;
        s2 += p;
      }
    s2 += __shfl_xor(s2, 16); s2 += __shfl_xor(s2, 32);
    const float inv2 = 1.0f / s2;
#pragma unroll
    for (int kf = 0; kf < 8; ++kf)
      pk[kf] = {(__bf16)(sacc[kf][0] * inv2), (__bf16)(sacc[kf][1] * inv2),
                (__bf16)(sacc[kf][2] * inv2), (__bf16)(sacc[kf][3] * inv2)};
  }

  // ---- PV in two column-halves through the 16KB ps buffer (wave-local rows;
  // lgkm fences only, no block barrier; rule #18 sched_barrier after each).
  f32x4 xacc[4] = {};
#pragma unroll
  for (int half = 0; half < 2; ++half) {
#pragma unroll
    for (int kf = 0; kf < 4; ++kf) {
      const int gi = (kf * 4 + g) ^ ((q & 3) << 2);
      *(bf16x4*)(smem + q * 128 + gi * 8) = pk[half * 4 + kf];
    }
    asm volatile("s_waitcnt lgkmcnt(0)" ::: "memory");
    __builtin_amdgcn_sched_barrier(0);
    __builtin_amdgcn_s_setprio(1);
#pragma unroll
    for (int k2 = 0; k2 < 2; ++k2) {
      const int ks2 = half * 2 + k2;
      const int gi = (k2 * 8 + g * 2) ^ ((q & 3) << 2);
      bf16x8 pa = *(const bf16x8*)(smem + q * 128 + gi * 8);
#pragma unroll
      for (int fc = 0; fc < 4; ++fc) {
        const int d = fc * 16 + cl;
        const int pg = (ks2 * 8 + 2 * g) ^ (((d >> 3) & 7) << 2);
        bf16x8 bv = *(const bf16x8*)&vt[d * 128 + pg * 4];
        xacc[fc] = __builtin_amdgcn_mfma_f32_16x16x32_bf16(pa, bv, xacc[fc], 0, 0, 0);
      }
    }
    __builtin_amdgcn_s_setprio(0);
    if (half == 0) {
      asm volatile("s_waitcnt lgkmcnt(0)" ::: "memory");   // half-0 reads drained
      __builtin_amdgcn_sched_barrier(0);
    }
  }

  // X-store via plain casts (compiler cvt_pk where possible)
#pragma unroll
  for (int fc = 0; fc < 4; ++fc)
#pragma unroll
    for (int e = 0; e < 4; ++e) {
      const int qr = wid * 16 + g * 4 + e;
      __bf16 b = (__bf16)xacc[fc][e];
      unsigned short u;
      __builtin_memcpy(&u, &b, 2);
      xout[base + (size_t)qr * DM + fc * 16 + cl] = u;
    }
}

extern "C" void kernel_launch(void* const* d_in, const int* in_sizes, int n_in,
                              void* d_out, int out_size, void* d_ws, size_t ws_size,
                              hipStream_t stream) {
  (void)in_sizes; (void)n_in; (void)out_size; (void)ws_size;
  const float* Q = (const float*)d_in[0];
  const float* K = (const float*)d_in[1];
  const float* V = (const float*)d_in[2];
  const float* mask = (const float*)d_in[3];
  const float* Wq = (const float*)d_in[4];
  const float* bq = (const float*)d_in[5];
  const float* Wk = (const float*)d_in[6];
  const float* bk = (const float*)d_in[7];
  const float* Wv = (const float*)d_in[8];
  const float* bv = (const float*)d_in[9];
  const float* Wo = (const float*)d_in[10];
  const float* bo = (const float*)d_in[11];

  const size_t NP = (size_t)65536 * DM;   // elements per [65536][768] bf16 buffer

  unsigned short* qp = (unsigned short*)d_out;
  unsigned short* kp = qp + NP;
  unsigned short* S1 = (unsigned short*)d_ws;
  unsigned short* S2 = S1 + NP;
  unsigned short* wt = S2 + NP;                 // [4][768*768] bf16
  float* mm = (float*)(wt + (size_t)4 * DM * DM);

  prep_w<<<dim3(24, 24, 4), 256, 0, stream>>>(Wq, Wk, Wv, Wo, wt);
  prep_m<<<dim3(128), 64, 0, stream>>>(mask, mm);

  const int n8 = (int)(NP / 8);

  // Q and K paths are independent: one conv launch, one batched gemm launch.
  convb2<<<dim3(2048, 2), 256, 0, stream>>>(Q, K, S1, S2, n8);
  gemm8x2<<<dim3(768, 2), 512, 0, stream>>>(S1, wt + 0 * (size_t)DM * DM, bq, qp,
                                            S2, wt + 1 * (size_t)DM * DM, bk, kp);

  convb<<<dim3(2048), 256, 0, stream>>>(V, S1, n8);
  gemm8<true><<<dim3(768), 512, 0, stream>>>(S1, wt + 2 * (size_t)DM * DM, bv, S2);

  attn_k<<<dim3(12, 512), 512, 0, stream>>>(qp, kp, S2, mm, S2);

  gemm8<false><<<dim3(768), 512, 0, stream>>>(S2, wt + 3 * (size_t)DM * DM, bo,
                                              (float*)d_out);
}

// Round 7
// 667.848 us; speedup vs baseline: 1.0022x; 1.0022x over previous
//
#include <hip/hip_runtime.h>

// MultiHeadedAttention: out = ((softmax(softmax(QK^T/8)+softmax(mask/128)))V) @ Wo
// Q,K,V (128,512,768) fp32 -> flat [65536][768]. Attention slice (l,h) = rows
// l*128..+127, cols h*64..+63 of the flat projection buffers.
// R6 post-mortem: gemm8x2 batching neutral (reverted to R5 launcher); clean
// counters show gemm8 at MfmaUtil 36% = the documented 2-barrier-per-K-step
// structural ceiling. This round (single variable): port gemm8's K-loop to the
// 256^2 8-phase schedule (T3+T4 counted vmcnt) keeping tile/waves/acc/swizzle/
// epilogue identical. BK=64 (2 K32 substeps); LDS = per-operand
// [parity][half][substep] 8KB sub-blocks (128KB total); 6 iters x 8 phases;
// each phase {frag ds_reads + 1-2 half-tile stages -> barrier -> 16 MFMA ->
// barrier}; vmcnt(4) ONLY at ph4/ph8 (drain arithmetic: 12 ops outstanding,
// completes exactly the units consumed in the next 4 phases; one-phase-gap
// rule seals every WAR via the phase-end barrier). Accumulation K-order
// unchanged -> same numerics.
//   convb: fp32->bf16 L3-staging. attn: R1-proven (32KB, ps column-halves,
//   exp2-folded dual softmax, ~123us).

typedef __attribute__((ext_vector_type(8))) __bf16 bf16x8;
typedef __attribute__((ext_vector_type(4))) __bf16 bf16x4;
typedef __attribute__((ext_vector_type(4))) float f32x4;

#define DM 768
#define LOG2E 1.44269504f

__device__ __forceinline__ unsigned short f2bf(float x) {
  unsigned u = __float_as_uint(x);
  u += 0x7FFFu + ((u >> 16) & 1u);   // RNE
  return (unsigned short)(u >> 16);
}

__device__ __forceinline__ void gl_lds16(const void* g, void* l) {
  __builtin_amdgcn_global_load_lds(
      (const __attribute__((address_space(1))) unsigned int*)g,
      (__attribute__((address_space(3))) unsigned int*)l, 16, 0, 0);
}

__device__ __forceinline__ void waitvm(int n) {
  if (n == 0) asm volatile("s_waitcnt vmcnt(0)" ::: "memory");
  else        asm volatile("s_waitcnt vmcnt(4)" ::: "memory");
}

// ---------------- prep: transpose+convert 4 weights to bf16 [op][n][k] ----------------
__global__ __launch_bounds__(256) void prep_w(const float* __restrict__ w0,
                                              const float* __restrict__ w1,
                                              const float* __restrict__ w2,
                                              const float* __restrict__ w3,
                                              unsigned short* __restrict__ wt) {
  __shared__ float t[32][33];
  const int op = blockIdx.z;
  const float* w = (op == 0) ? w0 : (op == 1) ? w1 : (op == 2) ? w2 : w3;
  unsigned short* o = wt + (size_t)op * DM * DM;
  const int n0 = blockIdx.x * 32, k0 = blockIdx.y * 32;
  const int tx = threadIdx.x & 31, ty = threadIdx.x >> 5;   // ty 0..7
#pragma unroll
  for (int r = 0; r < 4; ++r)
    t[r * 8 + ty][tx] = w[(size_t)(k0 + r * 8 + ty) * DM + n0 + tx];
  __syncthreads();
#pragma unroll
  for (int r = 0; r < 4; ++r)
    o[(size_t)(n0 + r * 8 + ty) * DM + k0 + tx] = f2bf(t[tx][r * 8 + ty]);
}

// ------- prep: mm = softmax(mask/128, axis=-1) * log2e, fp32 [128][128] ---------------
__global__ void prep_m(const float* __restrict__ mask, float* __restrict__ mm) {
  int row = blockIdx.x;
  int t = threadIdx.x;  // 64 threads
  float a = mask[row * 128 + t] * (1.0f / 128.0f);
  float b = mask[row * 128 + t + 64] * (1.0f / 128.0f);
  float mx = fmaxf(a, b);
  for (int s = 1; s < 64; s <<= 1) mx = fmaxf(mx, __shfl_xor(mx, s));
  float ea = __expf(a - mx), eb = __expf(b - mx);
  float sum = ea + eb;
  for (int s = 1; s < 64; s <<= 1) sum += __shfl_xor(sum, s);
  float inv = LOG2E / sum;               // prescale by log2e for attn's exp2 path
  mm[row * 128 + t] = ea * inv;
  mm[row * 128 + t + 64] = eb * inv;
}

// ---------------- conv: fp32 -> bf16, vectorized (8 elems/thread/iter) ----------------
__global__ __launch_bounds__(256) void convb(const float* __restrict__ in,
                                             unsigned short* __restrict__ out, int n8) {
  int i = blockIdx.x * 256 + threadIdx.x;
  const int stride = gridDim.x * 256;
  for (; i < n8; i += stride) {
    const float4 a = ((const float4*)in)[(size_t)i * 2];
    const float4 b = ((const float4*)in)[(size_t)i * 2 + 1];
    ushort4 lo = {f2bf(a.x), f2bf(a.y), f2bf(a.z), f2bf(a.w)};
    ushort4 hi = {f2bf(b.x), f2bf(b.y), f2bf(b.z), f2bf(b.w)};
    ((ushort4*)out)[(size_t)i * 2] = lo;
    ((ushort4*)out)[(size_t)i * 2 + 1] = hi;
  }
}

// ------------- gemm8: [65536 x 768] bf16 A @ [768 x 768] Bt, 8-phase schedule ---------
// K = 768 = 12 K64-tiles T (2 K32 substeps each) = 6 iterations x {T0=2i, T1=2i+1}.
// Per iter, phases consume quadrants in order (m0-3,n0-1)->(m4-7,n0-1)->(m4-7,n2-3)
// ->(m0-3,n2-3) for T0 (ph1-4) then T1 (ph5-8); A frags 0-3 re-read at ph4/ph8.
// Stage slots (one-phase gap after the overwritten buffer's last read):
//   ph1: A[2i+1,h0] (i>=1)   ph2: A[2i+1,h1] (i>=1)
//   ph4: B[2i+2,h0]+B[2i+2,h1] + vmcnt(4)   ph5: A[2i+2,h0]   ph6: A[2i+2,h1]
//   ph8: B[2i+3,h0]+B[2i+3,h1] + vmcnt(4)        (slots ph4..ph8 active i<=4)
// Drain check (2 ops/unit): at ph4 outstanding {B[2i+1]x2, A[2i+1]x2, B[2i+2]x2}
// = 12 ops -> vmcnt(4) completes exactly through A[2i+1] (consumed ph5-8).
// At ph8: {B[2i+2]x2, A[2i+2]x2, B[2i+3]x2} = 12 -> completes through A[2i+2]
// (consumed ph1-4 of i+1). Last iter: ph4 -> vmcnt(0), ph8 no wait.
template <bool OUT_BF16>
__global__ __launch_bounds__(512, 2) void gemm8(const unsigned short* __restrict__ A,
                                                const unsigned short* __restrict__ Bt,
                                                const float* __restrict__ bias,
                                                void* __restrict__ Outp) {
  __shared__ char smem[131072];   // A sub-blocks @0 (8x8KB), B @65536 (8x8KB)
  const int tid = threadIdx.x, lane = tid & 63, wid = tid >> 6;
  const int cl = lane & 15, g = lane >> 4;
  const int wm = wid >> 2, wn = wid & 3;
  const int bid = blockIdx.x;
  const int xcd = bid & 7, bi = bid >> 3;        // 768 = 8 xcd * (32 m * 3 n)
  const int m0 = (xcd * 32 + bi / 3) * 256;
  const int n0 = (bi % 3) * 256;

  f32x4 acc[8][4] = {};

  // sub-block = [128 rows][32 k] bf16, 8KB, same 16B-slot swizzle as the proven
  // kernel: logical k-granule sl of row r stored at phys slot sl^((r>>1)&3).
  auto abase = [&](int par, int h, int ss) -> char* {
    return smem + ((par * 2 + h) * 2 + ss) * 8192;
  };
  auto bbase = [&](int par, int h, int ss) -> char* {
    return smem + 65536 + ((par * 2 + h) * 2 + ss) * 8192;
  };

  // stage one half-tile unit (128 rows x 64 k = 2 sub-blocks, 2 gl_lds/thread)
  auto stage_u = [&](const unsigned short* src, int rb, int T, int h, char* d0,
                     char* d1) {
    const int row = wid * 16 + (lane >> 2);
    const int slot = lane & 3;
    const size_t gaddr = (size_t)(rb + h * 128 + row) * DM + T * 64 +
                         ((slot ^ ((row >> 1) & 3)) * 8);
    gl_lds16(src + gaddr, d0 + wid * 1024);
    gl_lds16(src + gaddr + 32, d1 + wid * 1024);
  };

  auto ldaf = [&](bf16x8 (*af)[2], int par, int f0) {   // A frags f0..f0+3, ss 0,1
#pragma unroll
    for (int mi = 0; mi < 4; ++mi) {
      const int lr = (f0 + mi) * 16 + cl;
      const int gi = (g ^ ((lr >> 1) & 3)) * 16;
#pragma unroll
      for (int ss = 0; ss < 2; ++ss)
        af[mi][ss] = *(const bf16x8*)(abase(par, wm, ss) + lr * 64 + gi);
    }
  };
  auto ldbf = [&](bf16x8 (*bf)[2], int par, int nf0) {  // B frags nf0..nf0+1
#pragma unroll
    for (int ni = 0; ni < 2; ++ni) {
      const int lr = (wn & 1) * 64 + (nf0 + ni) * 16 + cl;
      const int gi = (g ^ ((lr >> 1) & 3)) * 16;
#pragma unroll
      for (int ss = 0; ss < 2; ++ss)
        bf[ni][ss] = *(const bf16x8*)(bbase(par, wn >> 1, ss) + lr * 64 + gi);
    }
  };
  auto mf16 = [&](bf16x8 (*af)[2], bf16x8 (*bf)[2], int f0, int nf0) {
    __builtin_amdgcn_s_setprio(1);
#pragma unroll
    for (int ss = 0; ss < 2; ++ss)
#pragma unroll
      for (int mi = 0; mi < 4; ++mi)
#pragma unroll
        for (int ni = 0; ni < 2; ++ni)
          acc[f0 + mi][nf0 + ni] = __builtin_amdgcn_mfma_f32_16x16x32_bf16(
              af[mi][ss], bf[ni][ss], acc[f0 + mi][nf0 + ni], 0, 0, 0);
    __builtin_amdgcn_s_setprio(0);
  };

  // ---- prologue: tiles 0,1 fully staged (8 units, 16 ops), landed.
#pragma unroll
  for (int T = 0; T < 2; ++T)
#pragma unroll
    for (int h = 0; h < 2; ++h) {
      stage_u(A, m0, T, h, abase(T, h, 0), abase(T, h, 1));
      stage_u(Bt, n0, T, h, bbase(T, h, 0), bbase(T, h, 1));
    }
  waitvm(0);
  __builtin_amdgcn_s_barrier();

#pragma unroll 1
  for (int i = 0; i < 6; ++i) {
    const int T1 = 2 * i + 1;
    const bool sA = (i >= 1);   // ph1/ph2 stage A[2i+1] (iter 0: prologue has it)
    const bool sF = (i <= 4);   // ph4/5/6/8 stage tiles 2i+2, 2i+3
    bf16x8 afA[4][2], afB[4][2], bfA[2][2], bfB[2][2];

    // ph1: Q(m0-3, n0-1) of T0
    ldaf(afA, 0, 0);
    ldbf(bfA, 0, 0);
    if (sA) stage_u(A, m0, T1, 0, abase(1, 0, 0), abase(1, 0, 1));
    __builtin_amdgcn_s_barrier();
    mf16(afA, bfA, 0, 0);
    __builtin_amdgcn_s_barrier();

    // ph2: Q(m4-7, n0-1)
    ldaf(afB, 0, 4);
    if (sA) stage_u(A, m0, T1, 1, abase(1, 1, 0), abase(1, 1, 1));
    __builtin_amdgcn_s_barrier();
    mf16(afB, bfA, 4, 0);
    __builtin_amdgcn_s_barrier();

    // ph3: Q(m4-7, n2-3)
    ldbf(bfB, 0, 2);
    __builtin_amdgcn_s_barrier();
    mf16(afB, bfB, 4, 2);
    __builtin_amdgcn_s_barrier();

    // ph4: Q(m0-3, n2-3); stage B[2i+2] both halves; counted drain
    ldaf(afA, 0, 0);
    if (sF) {
      stage_u(Bt, n0, T1 + 1, 0, bbase(0, 0, 0), bbase(0, 0, 1));
      stage_u(Bt, n0, T1 + 1, 1, bbase(0, 1, 0), bbase(0, 1, 1));
      waitvm(4);
    } else {
      waitvm(0);
    }
    __builtin_amdgcn_s_barrier();
    mf16(afA, bfB, 0, 2);
    __builtin_amdgcn_s_barrier();

    // ph5: Q(m0-3, n0-1) of T1
    ldaf(afA, 1, 0);
    ldbf(bfA, 1, 0);
    if (sF) stage_u(A, m0, T1 + 1, 0, abase(0, 0, 0), abase(0, 0, 1));
    __builtin_amdgcn_s_barrier();
    mf16(afA, bfA, 0, 0);
    __builtin_amdgcn_s_barrier();

    // ph6: Q(m4-7, n0-1)
    ldaf(afB, 1, 4);
    if (sF) stage_u(A, m0, T1 + 1, 1, abase(0, 1, 0), abase(0, 1, 1));
    __builtin_amdgcn_s_barrier();
    mf16(afB, bfA, 4, 0);
    __builtin_amdgcn_s_barrier();

    // ph7: Q(m4-7, n2-3)
    ldbf(bfB, 1, 2);
    __builtin_amdgcn_s_barrier();
    mf16(afB, bfB, 4, 2);
    __builtin_amdgcn_s_barrier();

    // ph8: Q(m0-3, n2-3); stage B[2i+3] both halves; counted drain
    ldaf(afA, 1, 0);
    if (sF) {
      stage_u(Bt, n0, T1 + 2, 0, bbase(1, 0, 0), bbase(1, 0, 1));
      stage_u(Bt, n0, T1 + 2, 1, bbase(1, 1, 0), bbase(1, 1, 1));
      waitvm(4);
    }
    __builtin_amdgcn_s_barrier();
    mf16(afA, bfB, 0, 2);
    __builtin_amdgcn_s_barrier();
  }

  float bb[4];
#pragma unroll
  for (int ni = 0; ni < 4; ++ni) bb[ni] = bias[n0 + wn * 64 + ni * 16 + cl];
#pragma unroll
  for (int mi = 0; mi < 8; ++mi) {
    const int row = m0 + wm * 128 + mi * 16 + g * 4;
#pragma unroll
    for (int ni = 0; ni < 4; ++ni) {
      const int col = n0 + wn * 64 + ni * 16 + cl;
#pragma unroll
      for (int e = 0; e < 4; ++e) {
        float v = acc[mi][ni][e] + bb[ni];
        if constexpr (OUT_BF16)
          ((unsigned short*)Outp)[(size_t)(row + e) * DM + col] = f2bf(v);
        else
          ((float*)Outp)[(size_t)(row + e) * DM + col] = v;
      }
    }
  }
}

// ---------------- attention: 8 waves x 16 q-rows, swapped QK^T, exp2 softmax ----------
__global__ __launch_bounds__(512) void attn_k(const unsigned short* __restrict__ qp,
                                              const unsigned short* __restrict__ kp,
                                              const unsigned short* __restrict__ vp,
                                              const float* __restrict__ mm,
                                              unsigned short* __restrict__ xout) {
  __shared__ char smem[32768];
  // [0,16384): ks [128][64] bf16, 16B-granule XOR swizzle (gi ^= row&7); after
  //            the post-QK^T barrier, reused as ps [128][64] bf16 COLUMN-HALF
  //            of P (two passes: cols 0..63 then 64..127), 8B granules,
  //            gi ^= (q&3)<<2.
  // [16384,32768): vt [64][128] bf16, 4-elem granule swizzle (R1-proven):
  //            phys = kq ^ ((d>>3)<<2).
  unsigned short* vt = (unsigned short*)(smem + 16384);

  const int tid = threadIdx.x, lane = tid & 63, wid = tid >> 6;
  const int cl = lane & 15, g = lane >> 4;
  const int h = blockIdx.x, l = blockIdx.y;
  const size_t base = (size_t)l * 128 * DM + h * 64;
  const int q = wid * 16 + cl;                   // this lane's q-row

#pragma unroll
  for (int p = 0; p < 2; ++p) {
    const int chunk = p * 8 + wid;              // 0..15, 1KB each
    const int row = chunk * 8 + (lane >> 3);    // 128B rows
    const int gi = (lane & 7) ^ (row & 7);
    gl_lds16(kp + base + (size_t)row * DM + gi * 8, smem + chunk * 1024);
  }
  if (tid < 256) {
    const int dc = (tid & 7) * 8;
    const int kq = tid >> 3;
    const int pg = (kq ^ ((tid & 7) << 2));
    int4 r0 = *(const int4*)&vp[base + (size_t)(kq * 4 + 0) * DM + dc];
    int4 r1 = *(const int4*)&vp[base + (size_t)(kq * 4 + 1) * DM + dc];
    int4 r2 = *(const int4*)&vp[base + (size_t)(kq * 4 + 2) * DM + dc];
    int4 r3 = *(const int4*)&vp[base + (size_t)(kq * 4 + 3) * DM + dc];
    const unsigned short* u0 = (const unsigned short*)&r0;
    const unsigned short* u1 = (const unsigned short*)&r1;
    const unsigned short* u2 = (const unsigned short*)&r2;
    const unsigned short* u3 = (const unsigned short*)&r3;
#pragma unroll
    for (int j = 0; j < 8; ++j) {
      ushort4 w = {u0[j], u1[j], u2[j], u3[j]};
      *(ushort4*)&vt[(dc + j) * 128 + pg * 4] = w;
    }
  }
  bf16x8 qf[2];
#pragma unroll
  for (int ksr = 0; ksr < 2; ++ksr)
    qf[ksr] = *(const bf16x8*)&qp[base + (size_t)q * DM + ksr * 32 + g * 8];
  __syncthreads();

  f32x4 sacc[8] = {};
  __builtin_amdgcn_s_setprio(1);
#pragma unroll
  for (int ksr = 0; ksr < 2; ++ksr) {
#pragma unroll
    for (int kf = 0; kf < 8; ++kf) {
      const int row = kf * 16 + cl;
      const int gi = (ksr * 4 + g) ^ (row & 7);
      bf16x8 kfr = *(const bf16x8*)(smem + row * 128 + gi * 16);
      sacc[kf] = __builtin_amdgcn_mfma_f32_16x16x32_bf16(kfr, qf[ksr], sacc[kf], 0, 0, 0);
    }
  }
  __builtin_amdgcn_s_setprio(0);
  __syncthreads();   // all waves' ks reads done before any ps write (ps aliases ks)

  // ---- dual softmax, exp2-folded, no max subtraction (inputs bounded)
  bf16x4 pk[8];
  {
    float4 mrow[8];
#pragma unroll
    for (int kf = 0; kf < 8; ++kf)
      mrow[kf] = *(const float4*)&mm[q * 128 + kf * 16 + g * 4];
    float sm = 0.f;
#pragma unroll
    for (int kf = 0; kf < 8; ++kf)
#pragma unroll
      for (int e = 0; e < 4; ++e) {
        float p = exp2f(sacc[kf][e] * (0.125f * LOG2E));   // = exp(s/8)
        sacc[kf][e] = p;
        sm += p;
      }
    sm += __shfl_xor(sm, 16); sm += __shfl_xor(sm, 32);
    const float inv2e = LOG2E / sm;
    float s2 = 0.f;
#pragma unroll
    for (int kf = 0; kf < 8; ++kf)
#pragma unroll
      for (int e = 0; e < 4; ++e) {
        // mrow prescaled by log2e: exp(p/sm + m) = exp2(p*inv2e + m*log2e)
        float p = exp2f(fmaf(sacc[kf][e], inv2e, ((const float*)&mrow[kf])[e]));
        sacc[kf][e] = p;
        s2 += p;
      }
    s2 += __shfl_xor(s2, 16); s2 += __shfl_xor(s2, 32);
    const float inv2 = 1.0f / s2;
#pragma unroll
    for (int kf = 0; kf < 8; ++kf)
      pk[kf] = {(__bf16)(sacc[kf][0] * inv2), (__bf16)(sacc[kf][1] * inv2),
                (__bf16)(sacc[kf][2] * inv2), (__bf16)(sacc[kf][3] * inv2)};
  }

  // ---- PV in two column-halves through the 16KB ps buffer (wave-local rows;
  // lgkm fences only, no block barrier; rule #18 sched_barrier after each).
  f32x4 xacc[4] = {};
#pragma unroll
  for (int half = 0; half < 2; ++half) {
#pragma unroll
    for (int kf = 0; kf < 4; ++kf) {
      const int gi = (kf * 4 + g) ^ ((q & 3) << 2);
      *(bf16x4*)(smem + q * 128 + gi * 8) = pk[half * 4 + kf];
    }
    asm volatile("s_waitcnt lgkmcnt(0)" ::: "memory");
    __builtin_amdgcn_sched_barrier(0);
    __builtin_amdgcn_s_setprio(1);
#pragma unroll
    for (int k2 = 0; k2 < 2; ++k2) {
      const int ks2 = half * 2 + k2;
      const int gi = (k2 * 8 + g * 2) ^ ((q & 3) << 2);
      bf16x8 pa = *(const bf16x8*)(smem + q * 128 + gi * 8);
#pragma unroll
      for (int fc = 0; fc < 4; ++fc) {
        const int d = fc * 16 + cl;
        const int pg = (ks2 * 8 + 2 * g) ^ (((d >> 3) & 7) << 2);
        bf16x8 bv = *(const bf16x8*)&vt[d * 128 + pg * 4];
        xacc[fc] = __builtin_amdgcn_mfma_f32_16x16x32_bf16(pa, bv, xacc[fc], 0, 0, 0);
      }
    }
    __builtin_amdgcn_s_setprio(0);
    if (half == 0) {
      asm volatile("s_waitcnt lgkmcnt(0)" ::: "memory");   // half-0 reads drained
      __builtin_amdgcn_sched_barrier(0);
    }
  }

  // X-store via plain casts (compiler cvt_pk where possible)
#pragma unroll
  for (int fc = 0; fc < 4; ++fc)
#pragma unroll
    for (int e = 0; e < 4; ++e) {
      const int qr = wid * 16 + g * 4 + e;
      __bf16 b = (__bf16)xacc[fc][e];
      unsigned short u;
      __builtin_memcpy(&u, &b, 2);
      xout[base + (size_t)qr * DM + fc * 16 + cl] = u;
    }
}

extern "C" void kernel_launch(void* const* d_in, const int* in_sizes, int n_in,
                              void* d_out, int out_size, void* d_ws, size_t ws_size,
                              hipStream_t stream) {
  (void)in_sizes; (void)n_in; (void)out_size; (void)ws_size;
  const float* Q = (const float*)d_in[0];
  const float* K = (const float*)d_in[1];
  const float* V = (const float*)d_in[2];
  const float* mask = (const float*)d_in[3];
  const float* Wq = (const float*)d_in[4];
  const float* bq = (const float*)d_in[5];
  const float* Wk = (const float*)d_in[6];
  const float* bk = (const float*)d_in[7];
  const float* Wv = (const float*)d_in[8];
  const float* bv = (const float*)d_in[9];
  const float* Wo = (const float*)d_in[10];
  const float* bo = (const float*)d_in[11];

  const size_t NP = (size_t)65536 * DM;   // elements per [65536][768] bf16 buffer

  unsigned short* qp = (unsigned short*)d_out;
  unsigned short* kp = qp + NP;
  unsigned short* S1 = (unsigned short*)d_ws;
  unsigned short* S2 = S1 + NP;
  unsigned short* wt = S2 + NP;                 // [4][768*768] bf16
  float* mm = (float*)(wt + (size_t)4 * DM * DM);

  prep_w<<<dim3(24, 24, 4), 256, 0, stream>>>(Wq, Wk, Wv, Wo, wt);
  prep_m<<<dim3(128), 64, 0, stream>>>(mask, mm);

  const int n8 = (int)(NP / 8);
  dim3 g8(768);

  convb<<<dim3(2048), 256, 0, stream>>>(Q, S1, n8);
  gemm8<true><<<g8, 512, 0, stream>>>(S1, wt + 0 * (size_t)DM * DM, bq, qp);
  convb<<<dim3(2048), 256, 0, stream>>>(K, S1, n8);
  gemm8<true><<<g8, 512, 0, stream>>>(S1, wt + 1 * (size_t)DM * DM, bk, kp);
  convb<<<dim3(2048), 256, 0, stream>>>(V, S2, n8);
  gemm8<true><<<g8, 512, 0, stream>>>(S2, wt + 2 * (size_t)DM * DM, bv, S1);

  attn_k<<<dim3(12, 512), 512, 0, stream>>>(qp, kp, S1, mm, S1);

  gemm8<false><<<g8, 512, 0, stream>>>(S1, wt + 3 * (size_t)DM * DM, bo, (float*)d_out);
}